// Round 1
// baseline (940.574 us; speedup 1.0000x reference)
//
#include <hip/hip_runtime.h>
#include <hip/hip_bf16.h>
#include <math.h>
#include <stdint.h>

typedef __hip_bfloat16 bf16;
using f32x4 = __attribute__((ext_vector_type(4))) float;
using s16x8 = __attribute__((ext_vector_type(8))) short;

constexpr int Bc = 2, Sc = 2048, Hc = 2048, NHc = 32, HDc = 64;
constexpr int Mc = Bc * Sc;      // 4096 rows
constexpr int MAXPOS = 8192;

// ---------------- workspace layout (bytes) ----------------
constexpr size_t OFF_WV  = 0;                                    // Wv bf16   (H*H)
constexpr size_t OFF_WQK = OFF_WV  + (size_t)Hc * Hc * 2;        // Wqk bf16  (2H*H)
constexpr size_t OFF_WO  = OFF_WQK + (size_t)2 * Hc * Hc * 2;    // Wo bf16
constexpr size_t OFF_W1  = OFF_WO  + (size_t)Hc * Hc * 2;        // w1cat (1024 x 4096)
constexpr size_t OFF_W2  = OFF_W1  + (size_t)(Hc/2) * (2*Hc) * 2;// w2cat (2048 x 2048)
constexpr size_t OFF_HS  = OFF_W2  + (size_t)Hc * Hc * 2;        // hs bf16 (M x H)
constexpr size_t OFF_XPR = OFF_HS  + (size_t)Mc * Hc * 2;        // x shifted by 1 row
constexpr size_t OFF_O1  = OFF_XPR + (size_t)Mc * Hc * 2;        // o1   (M x 1024)
constexpr size_t OFF_O1P = OFF_O1  + (size_t)Mc * (Hc/2) * 2;    // o1 shifted
constexpr size_t OFF_O2  = OFF_O1P + (size_t)Mc * (Hc/2) * 2;    // o2+res fp32 (M x H)
constexpr size_t OFF_LF  = OFF_O2  + (size_t)Mc * Hc * 4;        // lf bf16
constexpr size_t OFF_VT  = OFF_LF  + (size_t)Mc * Hc * 2;        // V^T (b,h,d,s) bf16
constexpr size_t OFF_COS = OFF_VT  + (size_t)Mc * Hc * 2;        // cos table fp32
constexpr size_t OFF_SIN = OFF_COS + (size_t)MAXPOS * HDc * 4;
// aliases (lifetimes disjoint):
constexpr size_t OFF_QK  = OFF_O2;   // qk bf16 (M x 4096) over o2res
constexpr size_t OFF_Q   = OFF_XPR;  // q bf16 (b,h,s,d)   over xprev
constexpr size_t OFF_K   = OFF_HS;   // k bf16 (b,h,s,d)   over hs
constexpr size_t OFF_CTX = OFF_O1;   // ctx bf16 (b,s,h*d) over o1+o1prev
// total ≈ 164 MiB

// ---------------- helpers ----------------
__device__ __forceinline__ f32x4 mfma16(s16x8 a, s16x8 b, f32x4 c) {
  return __builtin_amdgcn_mfma_f32_16x16x32_bf16(a, b, c, 0, 0, 0);
}
__device__ __forceinline__ void gload16(const bf16* g, bf16* l) {
  __builtin_amdgcn_global_load_lds(
      (__attribute__((address_space(1))) void*)g,
      (__attribute__((address_space(3))) void*)l, 16, 0, 0);
}

// ---------------- small conversion kernels ----------------
__global__ void k_cvt(const float* __restrict__ in, bf16* __restrict__ out, int n) {
  int i = blockIdx.x * 256 + threadIdx.x;
  if (i < n) out[i] = __float2bfloat16(in[i]);
}

// hs fp32 -> hs bf16 and xprev (row-shifted, lf1 at s==0)
__global__ void k_cvt_hs(const float* __restrict__ hs, const float* __restrict__ lf1,
                         bf16* __restrict__ hsb, bf16* __restrict__ xprev) {
  int i = blockIdx.x * 256 + threadIdx.x;      // over M*H
  if (i >= Mc * Hc) return;
  float v = hs[i];
  bf16 b = __float2bfloat16(v);
  hsb[i] = b;
  int row = i >> 11, col = i & (Hc - 1);
  int s = row & (Sc - 1), bb = row >> 11;
  if (s + 1 < Sc) xprev[i + Hc] = b;
  if (s == 0)     xprev[i] = __float2bfloat16(lf1[bb * Hc + col]);
}

// w1cat[oc][k]: k<2048 tap0 (pairs xprev), k>=2048 tap1 (pairs x)
__global__ void k_repack1(const float* __restrict__ w, bf16* __restrict__ out) {
  int i = blockIdx.x * 256 + threadIdx.x;      // 1024*4096
  if (i >= (Hc/2) * 2 * Hc) return;
  int oc = i >> 12, k = i & 4095;
  int ic = k & (Hc - 1), t = k >> 11;
  out[i] = __float2bfloat16(w[((size_t)oc * Hc + ic) * 2 + t]);
}
// w2cat[c][k]: k<1024 tap0 (pairs o1prev), k>=1024 tap1 (pairs o1)
__global__ void k_repack2(const float* __restrict__ w, bf16* __restrict__ out) {
  int i = blockIdx.x * 256 + threadIdx.x;      // 2048*2048
  if (i >= Hc * Hc) return;
  int c = i >> 11, k = i & (Hc - 1);
  int oc = k & (Hc/2 - 1), t = k >> 10;
  out[i] = __float2bfloat16(w[((size_t)c * (Hc/2) + oc) * 2 + t]);
}

__global__ void k_prefill_o1p(const float* __restrict__ lf2, bf16* __restrict__ o1p) {
  int i = blockIdx.x * 256 + threadIdx.x;      // B * H/2
  if (i >= Bc * (Hc/2)) return;
  int b = i >> 10, n = i & (Hc/2 - 1);
  o1p[(size_t)b * Sc * (Hc/2) + n] = __float2bfloat16(lf2[i]);
}

struct InvF { double v[32]; double mscale; };

__global__ void k_costab(InvF f, float* __restrict__ ct, float* __restrict__ st) {
  int i = blockIdx.x * 256 + threadIdx.x;      // MAXPOS*64
  if (i >= MAXPOS * HDc) return;
  int p = i >> 6, d = i & 63;
  double ang = (double)p * f.v[d & 31];
  ct[i] = (float)(cos(ang) * f.mscale);
  st[i] = (float)(sin(ang) * f.mscale);
}

// ---------------- RMSNorm (block per row) ----------------
__global__ __launch_bounds__(256) void k_rmsnorm(const float* __restrict__ x,
                                                 const float* __restrict__ w,
                                                 bf16* __restrict__ out) {
  __shared__ float red[4];
  int row = blockIdx.x;
  const float* xr = x + (size_t)row * Hc;
  float ss = 0.f;
  for (int c = threadIdx.x; c < Hc; c += 256) { float v = xr[c]; ss += v * v; }
  for (int off = 32; off; off >>= 1) ss += __shfl_down(ss, off, 64);
  if ((threadIdx.x & 63) == 0) red[threadIdx.x >> 6] = ss;
  __syncthreads();
  float sc = rsqrtf((red[0] + red[1] + red[2] + red[3]) / Hc + 1e-6f);
  for (int c = threadIdx.x; c < Hc; c += 256)
    out[(size_t)row * Hc + c] = __float2bfloat16(xr[c] * sc * w[c]);
}

// ---------------- RoPE: qk (B,S,NH,128) -> q,k (b,h,s,d) ----------------
__global__ void k_rope(const bf16* __restrict__ qk, const int* __restrict__ pos,
                       const float* __restrict__ ct, const float* __restrict__ st,
                       bf16* __restrict__ qo, bf16* __restrict__ ko) {
  int i = blockIdx.x * 256 + threadIdx.x;      // M*NH*32
  if (i >= Mc * NHc * 32) return;
  int d = i & 31, h = (i >> 5) & 31, row = i >> 10;
  int p = pos[row];
  float c0 = ct[p * 64 + d],      s0 = st[p * 64 + d];
  float c1 = ct[p * 64 + 32 + d], s1 = st[p * 64 + 32 + d];
  const bf16* base = qk + (size_t)row * 4096 + h * 128;
  float q0 = __bfloat162float(base[d]),      q1 = __bfloat162float(base[d + 32]);
  float k0 = __bfloat162float(base[64 + d]), k1 = __bfloat162float(base[96 + d]);
  int b = row >> 11, s = row & (Sc - 1);
  size_t o = ((size_t)(b * NHc + h) * Sc + s) * 64 + d;
  qo[o]      = __float2bfloat16(q0 * c0 - q1 * s0);
  qo[o + 32] = __float2bfloat16(q1 * c1 + q0 * s1);
  ko[o]      = __float2bfloat16(k0 * c0 - k1 * s0);
  ko[o + 32] = __float2bfloat16(k1 * c1 + k0 * s1);
}

// ---------------- GEMM: C[M,N] = A[M,K] @ W[N,K]^T ----------------
// A is split at Ksplit between A0 (k<Ksplit) and A1; both have row stride Ksplit.
// EPI: 0 bf16 plain | 1 conv1 (+bias, dual store o1/o1prev) | 2 conv2 (+bias+resid, fp32)
//      3 v-transposed store (b,h,d,s) | 4 fp32 plain
template <int EPI>
__global__ __launch_bounds__(256) void gemm_bt(
    const bf16* __restrict__ A0, const bf16* __restrict__ A1, int Ksplit,
    const bf16* __restrict__ Bw, int K, int N, void* __restrict__ Cout,
    const float* __restrict__ bias, const float* __restrict__ resid,
    bf16* __restrict__ aux) {
  __shared__ __align__(16) bf16 As[128 * 32];
  __shared__ __align__(16) bf16 Bs[128 * 32];
  const int tid = threadIdx.x;
  const int bm = blockIdx.y, bn = blockIdx.x;
  const int w = tid >> 6, l = tid & 63;
  const int wm = (w >> 1) * 64, wn = (w & 1) * 64;
  const int lrow = l & 15, lg = l >> 4, lk = lg * 8;
  const int r0 = tid >> 2, cofs = (tid & 3) * 8;

  f32x4 acc[4][4] = {};
  const int nkt = K / 32;
  for (int kt = 0; kt < nkt; ++kt) {
    const int kcol = kt * 32;
    const bf16* Au; int kc;
    if (kcol < Ksplit) { Au = A0; kc = kcol; } else { Au = A1; kc = kcol - Ksplit; }
    __syncthreads();
    gload16(Au + (size_t)(bm * 128 + r0) * Ksplit + kc + cofs,       As + tid * 8);
    gload16(Au + (size_t)(bm * 128 + r0 + 64) * Ksplit + kc + cofs,  As + tid * 8 + 2048);
    gload16(Bw + (size_t)(bn * 128 + r0) * K + kcol + cofs,          Bs + tid * 8);
    gload16(Bw + (size_t)(bn * 128 + r0 + 64) * K + kcol + cofs,     Bs + tid * 8 + 2048);
    __syncthreads();
    s16x8 af[4], bfr[4];
#pragma unroll
    for (int m = 0; m < 4; ++m) af[m] = *(const s16x8*)&As[(wm + m * 16 + lrow) * 32 + lk];
#pragma unroll
    for (int n = 0; n < 4; ++n) bfr[n] = *(const s16x8*)&Bs[(wn + n * 16 + lrow) * 32 + lk];
#pragma unroll
    for (int m = 0; m < 4; ++m)
#pragma unroll
      for (int n = 0; n < 4; ++n)
        acc[m][n] = mfma16(af[m], bfr[n], acc[m][n]);
  }
#pragma unroll
  for (int m = 0; m < 4; ++m)
#pragma unroll
    for (int n = 0; n < 4; ++n)
#pragma unroll
      for (int r = 0; r < 4; ++r) {
        const int grow = bm * 128 + wm + m * 16 + lg * 4 + r;
        const int gcol = bn * 128 + wn + n * 16 + lrow;
        float v = acc[m][n][r];
        if constexpr (EPI == 0) {
          ((bf16*)Cout)[(size_t)grow * N + gcol] = __float2bfloat16(v);
        } else if constexpr (EPI == 1) {
          v += bias[gcol];
          bf16 bv = __float2bfloat16(v);
          ((bf16*)Cout)[(size_t)grow * N + gcol] = bv;
          if ((grow & (Sc - 1)) != Sc - 1) aux[(size_t)(grow + 1) * N + gcol] = bv;
        } else if constexpr (EPI == 2) {
          v += bias[gcol] + resid[(size_t)grow * N + gcol];
          ((float*)Cout)[(size_t)grow * N + gcol] = v;
        } else if constexpr (EPI == 3) {
          const int head = gcol >> 6, d = gcol & 63;
          const int b = grow >> 11, s = grow & (Sc - 1);
          ((bf16*)Cout)[((size_t)((b * NHc + head) * HDc + d)) * Sc + s] = __float2bfloat16(v);
        } else {
          ((float*)Cout)[(size_t)grow * N + gcol] = v;
        }
      }
}

// ---------------- causal flash attention ----------------
// Q,K: (b,h,s,d) bf16; Vt: (b,h,d,s) bf16; ctx out: (b,s,h*64+d) bf16
__global__ __launch_bounds__(256) void k_attn(const bf16* __restrict__ Q,
                                              const bf16* __restrict__ Kg,
                                              const bf16* __restrict__ Vt,
                                              bf16* __restrict__ ctx) {
  __shared__ __align__(16) bf16 Plds[4][16][32];
  const int tid = threadIdx.x;
  const int w = tid >> 6, l = tid & 63;
  const int lrow = l & 15, lg = l >> 4, lk = lg * 8;
  const int bh = blockIdx.y;
  const int q0 = blockIdx.x * 64 + w * 16;
  const bf16* Qp = Q  + (size_t)bh * Sc * HDc;
  const bf16* Kp = Kg + (size_t)bh * Sc * HDc;
  const bf16* Vp = Vt + (size_t)bh * HDc * Sc;

  const s16x8 qa0 = *(const s16x8*)&Qp[(size_t)(q0 + lrow) * 64 + lk];
  const s16x8 qa1 = *(const s16x8*)&Qp[(size_t)(q0 + lrow) * 64 + 32 + lk];

  f32x4 o[4] = {};
  float mrow[4] = {-1e30f, -1e30f, -1e30f, -1e30f};
  float lsum[4] = {0.f, 0.f, 0.f, 0.f};

  for (int kv0 = 0; kv0 < q0 + 16; kv0 += 32) {
    f32x4 sc[2];
#pragma unroll
    for (int c = 0; c < 2; ++c) {
      s16x8 kb0 = *(const s16x8*)&Kp[(size_t)(kv0 + c * 16 + lrow) * 64 + lk];
      s16x8 kb1 = *(const s16x8*)&Kp[(size_t)(kv0 + c * 16 + lrow) * 64 + 32 + lk];
      f32x4 z = {};
      z = mfma16(qa0, kb0, z);
      z = mfma16(qa1, kb1, z);
      sc[c] = z;
    }
#pragma unroll
    for (int r = 0; r < 4; ++r) {
      const int qrow = q0 + lg * 4 + r;
#pragma unroll
      for (int c = 0; c < 2; ++c) {
        const int kvcol = kv0 + c * 16 + lrow;
        const float sv = sc[c][r] * 0.125f;
        sc[c][r] = (kvcol <= qrow) ? sv : -1e30f;
      }
    }
#pragma unroll
    for (int r = 0; r < 4; ++r) {
      float t = fmaxf(sc[0][r], sc[1][r]);
#pragma unroll
      for (int off = 1; off < 16; off <<= 1) t = fmaxf(t, __shfl_xor(t, off, 64));
      const float mnew = fmaxf(mrow[r], t);
      const float sold = __expf(mrow[r] - mnew);
      mrow[r] = mnew;
      const float p0 = __expf(sc[0][r] - mnew);
      const float p1 = __expf(sc[1][r] - mnew);
      float ps = p0 + p1;
#pragma unroll
      for (int off = 1; off < 16; off <<= 1) ps += __shfl_xor(ps, off, 64);
      lsum[r] = lsum[r] * sold + ps;
#pragma unroll
      for (int db = 0; db < 4; ++db) o[db][r] *= sold;
      Plds[w][lg * 4 + r][lrow]      = __float2bfloat16(p0);
      Plds[w][lg * 4 + r][16 + lrow] = __float2bfloat16(p1);
    }
    const s16x8 pa = *(const s16x8*)&Plds[w][lrow][lk];
#pragma unroll
    for (int db = 0; db < 4; ++db) {
      s16x8 vb = *(const s16x8*)&Vp[(size_t)(db * 16 + lrow) * Sc + kv0 + lk];
      o[db] = mfma16(pa, vb, o[db]);
    }
  }
  const int b = bh >> 5, h = bh & 31;
#pragma unroll
  for (int r = 0; r < 4; ++r) {
    const float inv = 1.0f / lsum[r];
    const int qrow = q0 + lg * 4 + r;
#pragma unroll
    for (int db = 0; db < 4; ++db)
      ctx[((size_t)(b * Sc + qrow)) * Hc + h * 64 + db * 16 + lrow] =
          __float2bfloat16(o[db][r] * inv);
  }
}

// ---------------- host ----------------
extern "C" void kernel_launch(void* const* d_in, const int* in_sizes, int n_in,
                              void* d_out, int out_size, void* d_ws, size_t ws_size,
                              hipStream_t stream) {
  (void)in_sizes; (void)n_in; (void)out_size; (void)ws_size;
  const float* hs  = (const float*)d_in[0];
  const int*   pos = (const int*)d_in[1];
  const float* lf1 = (const float*)d_in[2];
  const float* lf2 = (const float*)d_in[3];
  const float* Wqk = (const float*)d_in[4];
  const float* Wv  = (const float*)d_in[5];
  const float* Wo  = (const float*)d_in[6];
  const float* c1w = (const float*)d_in[7];
  const float* c1b = (const float*)d_in[8];
  const float* c2w = (const float*)d_in[9];
  const float* c2b = (const float*)d_in[10];
  const float* lnw = (const float*)d_in[11];
  float* out = (float*)d_out;
  char*  ws  = (char*)d_ws;

  bf16* wvB   = (bf16*)(ws + OFF_WV);
  bf16* wqkB  = (bf16*)(ws + OFF_WQK);
  bf16* woB   = (bf16*)(ws + OFF_WO);
  bf16* w1B   = (bf16*)(ws + OFF_W1);
  bf16* w2B   = (bf16*)(ws + OFF_W2);
  bf16* hsB   = (bf16*)(ws + OFF_HS);
  bf16* xprB  = (bf16*)(ws + OFF_XPR);
  bf16* o1B   = (bf16*)(ws + OFF_O1);
  bf16* o1pB  = (bf16*)(ws + OFF_O1P);
  float* o2F  = (float*)(ws + OFF_O2);
  bf16* lfB   = (bf16*)(ws + OFF_LF);
  bf16* vtB   = (bf16*)(ws + OFF_VT);
  float* cosT = (float*)(ws + OFF_COS);
  float* sinT = (float*)(ws + OFF_SIN);
  bf16* qkB   = (bf16*)(ws + OFF_QK);
  bf16* qB    = (bf16*)(ws + OFF_Q);
  bf16* kB    = (bf16*)(ws + OFF_K);
  bf16* ctxB  = (bf16*)(ws + OFF_CTX);

  // YaRN inv_freq on host (fp64), matching the reference exactly
  InvF f;
  {
    const double base = 10000.0, scale = 2.0;
    const int hd = HDc;
    auto corr = [&](double nr) {
      return hd * log(8192.0 / (nr * 2.0 * M_PI)) / (2.0 * log(base));
    };
    double low = floor(corr(32.0)); if (low < 0) low = 0;
    double high = ceil(corr(1.0));  if (high > hd - 1) high = hd - 1;
    double hi = (low == high) ? high + 0.001 : high;
    for (int i = 0; i < 32; ++i) {
      double inv = 1.0 / pow(base, (2.0 * i) / hd);
      double ramp = ((double)i - low) / (hi - low);
      ramp = ramp < 0.0 ? 0.0 : (ramp > 1.0 ? 1.0 : ramp);
      double mask = 1.0 - ramp;
      f.v[i] = inv / ((1.0 - mask) * scale + mask);
    }
    f.mscale = 0.1 * log(scale) + 1.0;
  }

  // conversions / repacks / tables
  k_cvt<<<(Hc * Hc + 255) / 256, 256, 0, stream>>>(Wv, wvB, Hc * Hc);
  k_cvt<<<(2 * Hc * Hc + 255) / 256, 256, 0, stream>>>(Wqk, wqkB, 2 * Hc * Hc);
  k_cvt<<<(Hc * Hc + 255) / 256, 256, 0, stream>>>(Wo, woB, Hc * Hc);
  k_repack1<<<((Hc / 2) * 2 * Hc + 255) / 256, 256, 0, stream>>>(c1w, w1B);
  k_repack2<<<(Hc * Hc + 255) / 256, 256, 0, stream>>>(c2w, w2B);
  k_cvt_hs<<<(Mc * Hc + 255) / 256, 256, 0, stream>>>(hs, lf1, hsB, xprB);
  k_prefill_o1p<<<(Bc * (Hc / 2) + 255) / 256, 256, 0, stream>>>(lf2, o1pB);
  k_costab<<<(MAXPOS * HDc + 255) / 256, 256, 0, stream>>>(f, cosT, sinT);

  // conv1: o1 = [xprev|x] @ w1cat^T + b1   (dual store -> o1prev shifted)
  gemm_bt<1><<<dim3((Hc / 2) / 128, Mc / 128), 256, 0, stream>>>(
      xprB, hsB, Hc, w1B, 2 * Hc, Hc / 2, o1B, c1b, nullptr, o1pB);
  // v = hs @ Wv^T, stored transposed (b,h,d,s)
  gemm_bt<3><<<dim3(Hc / 128, Mc / 128), 256, 0, stream>>>(
      hsB, hsB, Hc, wvB, Hc, Hc, vtB, nullptr, nullptr, nullptr);
  // conv2: o2res = [o1prev|o1] @ w2cat^T + b2 + hidden  (fp32)
  gemm_bt<2><<<dim3(Hc / 128, Mc / 128), 256, 0, stream>>>(
      o1pB, o1B, Hc / 2, w2B, Hc, Hc, o2F, c2b, hs, nullptr);
  // lf = rmsnorm(o2res) * ln_w
  k_rmsnorm<<<Mc, 256, 0, stream>>>(o2F, lnw, lfB);
  // qk = lf @ Wqk^T   (bf16, over the o2res region)
  gemm_bt<0><<<dim3((2 * Hc) / 128, Mc / 128), 256, 0, stream>>>(
      lfB, lfB, Hc, wqkB, Hc, 2 * Hc, qkB, nullptr, nullptr, nullptr);
  // RoPE -> q,k (b,h,s,d)
  k_rope<<<(Mc * NHc * 32 + 255) / 256, 256, 0, stream>>>(qkB, pos, cosT, sinT, qB, kB);
  // causal flash attention -> ctx (b,s,h*64+d)
  k_attn<<<dim3(Sc / 64, Bc * NHc), 256, 0, stream>>>(qB, kB, vtB, ctxB);
  // out = ctx @ Wo^T  (fp32)
  gemm_bt<4><<<dim3(Hc / 128, Mc / 128), 256, 0, stream>>>(
      ctxB, ctxB, Hc, woB, Hc, Hc, out, nullptr, nullptr, nullptr);
}

// Round 2
// 625.265 us; speedup vs baseline: 1.5043x; 1.5043x over previous
//
#include <hip/hip_runtime.h>
#include <hip/hip_bf16.h>
#include <math.h>
#include <stdint.h>

typedef __hip_bfloat16 bf16;
using f32x4 = __attribute__((ext_vector_type(4))) float;
using s16x8 = __attribute__((ext_vector_type(8))) short;

constexpr int Bc = 2, Sc = 2048, Hc = 2048, NHc = 32, HDc = 64;
constexpr int Mc = Bc * Sc;      // 4096 rows
constexpr int MAXPOS = 8192;

// ---------------- workspace layout (bytes) ----------------
constexpr size_t OFF_WV  = 0;                                    // Wv bf16   (H*H)
constexpr size_t OFF_WQK = OFF_WV  + (size_t)Hc * Hc * 2;        // Wqk bf16  (2H*H)
constexpr size_t OFF_WO  = OFF_WQK + (size_t)2 * Hc * Hc * 2;    // Wo bf16
constexpr size_t OFF_W1  = OFF_WO  + (size_t)Hc * Hc * 2;        // w1cat (1024 x 4096)
constexpr size_t OFF_W2  = OFF_W1  + (size_t)(Hc/2) * (2*Hc) * 2;// w2cat (2048 x 2048)
constexpr size_t OFF_HS  = OFF_W2  + (size_t)Hc * Hc * 2;        // hs bf16 (M x H)
constexpr size_t OFF_XPR = OFF_HS  + (size_t)Mc * Hc * 2;        // x shifted by 1 row
constexpr size_t OFF_O1  = OFF_XPR + (size_t)Mc * Hc * 2;        // o1   (M x 1024)
constexpr size_t OFF_O1P = OFF_O1  + (size_t)Mc * (Hc/2) * 2;    // o1 shifted
constexpr size_t OFF_O2  = OFF_O1P + (size_t)Mc * (Hc/2) * 2;    // o2+res fp32 (M x H)
constexpr size_t OFF_LF  = OFF_O2  + (size_t)Mc * Hc * 4;        // lf bf16
constexpr size_t OFF_VT  = OFF_LF  + (size_t)Mc * Hc * 2;        // V^T (b,h,d,s) bf16
constexpr size_t OFF_COS = OFF_VT  + (size_t)Mc * Hc * 2;        // cos table fp32
constexpr size_t OFF_SIN = OFF_COS + (size_t)MAXPOS * HDc * 4;
// aliases (lifetimes disjoint):
constexpr size_t OFF_QK  = OFF_O2;   // qk bf16 (M x 4096) over o2res
constexpr size_t OFF_Q   = OFF_XPR;  // q bf16 (b,h,s,d)   over xprev
constexpr size_t OFF_K   = OFF_HS;   // k bf16 (b,h,s,d)   over hs
constexpr size_t OFF_CTX = OFF_O1;   // ctx bf16 (b,s,h*d) over o1+o1prev

// ---------------- helpers ----------------
__device__ __forceinline__ f32x4 mfma16(s16x8 a, s16x8 b, f32x4 c) {
  return __builtin_amdgcn_mfma_f32_16x16x32_bf16(a, b, c, 0, 0, 0);
}
__device__ __forceinline__ void gload16(const bf16* g, bf16* l) {
  __builtin_amdgcn_global_load_lds(
      (__attribute__((address_space(1))) void*)g,
      (__attribute__((address_space(3))) void*)l, 16, 0, 0);
}
__device__ __forceinline__ uint16_t bfbits(float x) {
  union { bf16 h; uint16_t u; } v; v.h = __float2bfloat16(x); return v.u;
}
__device__ __forceinline__ uint32_t pkbf(float a, float b) {
  return (uint32_t)bfbits(a) | ((uint32_t)bfbits(b) << 16);
}

// ---------------- small conversion kernels ----------------
__global__ void k_cvt(const float* __restrict__ in, bf16* __restrict__ out, int n) {
  int i = blockIdx.x * 256 + threadIdx.x;
  if (i < n) out[i] = __float2bfloat16(in[i]);
}

// hs fp32 -> hs bf16 and xprev (row-shifted, lf1 at s==0)
__global__ void k_cvt_hs(const float* __restrict__ hs, const float* __restrict__ lf1,
                         bf16* __restrict__ hsb, bf16* __restrict__ xprev) {
  int i = blockIdx.x * 256 + threadIdx.x;      // over M*H
  if (i >= Mc * Hc) return;
  float v = hs[i];
  bf16 b = __float2bfloat16(v);
  hsb[i] = b;
  int row = i >> 11, col = i & (Hc - 1);
  int s = row & (Sc - 1), bb = row >> 11;
  if (s + 1 < Sc) xprev[i + Hc] = b;
  if (s == 0)     xprev[i] = __float2bfloat16(lf1[bb * Hc + col]);
}

// w1cat[oc][k]: k<2048 tap0 (pairs xprev), k>=2048 tap1 (pairs x)
__global__ void k_repack1(const float* __restrict__ w, bf16* __restrict__ out) {
  int i = blockIdx.x * 256 + threadIdx.x;      // 1024*4096
  if (i >= (Hc/2) * 2 * Hc) return;
  int oc = i >> 12, k = i & 4095;
  int ic = k & (Hc - 1), t = k >> 11;
  out[i] = __float2bfloat16(w[((size_t)oc * Hc + ic) * 2 + t]);
}
// w2cat[c][k]: k<1024 tap0 (pairs o1prev), k>=1024 tap1 (pairs o1)
__global__ void k_repack2(const float* __restrict__ w, bf16* __restrict__ out) {
  int i = blockIdx.x * 256 + threadIdx.x;      // 2048*2048
  if (i >= Hc * Hc) return;
  int c = i >> 11, k = i & (Hc - 1);
  int oc = k & (Hc/2 - 1), t = k >> 10;
  out[i] = __float2bfloat16(w[((size_t)c * (Hc/2) + oc) * 2 + t]);
}

__global__ void k_prefill_o1p(const float* __restrict__ lf2, bf16* __restrict__ o1p) {
  int i = blockIdx.x * 256 + threadIdx.x;      // B * H/2
  if (i >= Bc * (Hc/2)) return;
  int b = i >> 10, n = i & (Hc/2 - 1);
  o1p[(size_t)b * Sc * (Hc/2) + n] = __float2bfloat16(lf2[i]);
}

struct InvF { double v[32]; double mscale; };

__global__ void k_costab(InvF f, float* __restrict__ ct, float* __restrict__ st) {
  int i = blockIdx.x * 256 + threadIdx.x;      // MAXPOS*64
  if (i >= MAXPOS * HDc) return;
  int p = i >> 6, d = i & 63;
  double ang = (double)p * f.v[d & 31];
  ct[i] = (float)(cos(ang) * f.mscale);
  st[i] = (float)(sin(ang) * f.mscale);
}

// ---------------- RMSNorm (block per row) ----------------
__global__ __launch_bounds__(256) void k_rmsnorm(const float* __restrict__ x,
                                                 const float* __restrict__ w,
                                                 bf16* __restrict__ out) {
  __shared__ float red[4];
  int row = blockIdx.x;
  const float* xr = x + (size_t)row * Hc;
  float ss = 0.f;
  for (int c = threadIdx.x; c < Hc; c += 256) { float v = xr[c]; ss += v * v; }
  for (int off = 32; off; off >>= 1) ss += __shfl_down(ss, off, 64);
  if ((threadIdx.x & 63) == 0) red[threadIdx.x >> 6] = ss;
  __syncthreads();
  float sc = rsqrtf((red[0] + red[1] + red[2] + red[3]) / Hc + 1e-6f);
  for (int c = threadIdx.x; c < Hc; c += 256)
    out[(size_t)row * Hc + c] = __float2bfloat16(xr[c] * sc * w[c]);
}

// ---------------- RoPE: qk (B,S,NH,128) -> q,k (b,h,s,d) ----------------
// q is pre-scaled by 1/sqrt(HD) = 0.125 so attention skips the scale.
__global__ void k_rope(const bf16* __restrict__ qk, const int* __restrict__ pos,
                       const float* __restrict__ ct, const float* __restrict__ st,
                       bf16* __restrict__ qo, bf16* __restrict__ ko) {
  int i = blockIdx.x * 256 + threadIdx.x;      // M*NH*32
  if (i >= Mc * NHc * 32) return;
  int d = i & 31, h = (i >> 5) & 31, row = i >> 10;
  int p = pos[row];
  float c0 = ct[p * 64 + d],      s0 = st[p * 64 + d];
  float c1 = ct[p * 64 + 32 + d], s1 = st[p * 64 + 32 + d];
  const bf16* base = qk + (size_t)row * 4096 + h * 128;
  float q0 = __bfloat162float(base[d]),      q1 = __bfloat162float(base[d + 32]);
  float k0 = __bfloat162float(base[64 + d]), k1 = __bfloat162float(base[96 + d]);
  int b = row >> 11, s = row & (Sc - 1);
  size_t o = ((size_t)(b * NHc + h) * Sc + s) * 64 + d;
  qo[o]      = __float2bfloat16((q0 * c0 - q1 * s0) * 0.125f);
  qo[o + 32] = __float2bfloat16((q1 * c1 + q0 * s1) * 0.125f);
  ko[o]      = __float2bfloat16(k0 * c0 - k1 * s0);
  ko[o + 32] = __float2bfloat16(k1 * c1 + k0 * s1);
}

// ---------------- GEMM: C[M,N] = A[M,K] @ W[N,K]^T ----------------
template <int EPI>
__global__ __launch_bounds__(256) void gemm_bt(
    const bf16* __restrict__ A0, const bf16* __restrict__ A1, int Ksplit,
    const bf16* __restrict__ Bw, int K, int N, void* __restrict__ Cout,
    const float* __restrict__ bias, const float* __restrict__ resid,
    bf16* __restrict__ aux) {
  __shared__ __align__(16) bf16 As[128 * 32];
  __shared__ __align__(16) bf16 Bs[128 * 32];
  const int tid = threadIdx.x;
  const int bm = blockIdx.y, bn = blockIdx.x;
  const int w = tid >> 6, l = tid & 63;
  const int wm = (w >> 1) * 64, wn = (w & 1) * 64;
  const int lrow = l & 15, lg = l >> 4, lk = lg * 8;
  const int r0 = tid >> 2, cofs = (tid & 3) * 8;

  f32x4 acc[4][4] = {};
  const int nkt = K / 32;
  for (int kt = 0; kt < nkt; ++kt) {
    const int kcol = kt * 32;
    const bf16* Au; int kc;
    if (kcol < Ksplit) { Au = A0; kc = kcol; } else { Au = A1; kc = kcol - Ksplit; }
    __syncthreads();
    gload16(Au + (size_t)(bm * 128 + r0) * Ksplit + kc + cofs,       As + tid * 8);
    gload16(Au + (size_t)(bm * 128 + r0 + 64) * Ksplit + kc + cofs,  As + tid * 8 + 2048);
    gload16(Bw + (size_t)(bn * 128 + r0) * K + kcol + cofs,          Bs + tid * 8);
    gload16(Bw + (size_t)(bn * 128 + r0 + 64) * K + kcol + cofs,     Bs + tid * 8 + 2048);
    __syncthreads();
    s16x8 af[4], bfr[4];
#pragma unroll
    for (int m = 0; m < 4; ++m) af[m] = *(const s16x8*)&As[(wm + m * 16 + lrow) * 32 + lk];
#pragma unroll
    for (int n = 0; n < 4; ++n) bfr[n] = *(const s16x8*)&Bs[(wn + n * 16 + lrow) * 32 + lk];
#pragma unroll
    for (int m = 0; m < 4; ++m)
#pragma unroll
      for (int n = 0; n < 4; ++n)
        acc[m][n] = mfma16(af[m], bfr[n], acc[m][n]);
  }
#pragma unroll
  for (int m = 0; m < 4; ++m)
#pragma unroll
    for (int n = 0; n < 4; ++n)
#pragma unroll
      for (int r = 0; r < 4; ++r) {
        const int grow = bm * 128 + wm + m * 16 + lg * 4 + r;
        const int gcol = bn * 128 + wn + n * 16 + lrow;
        float v = acc[m][n][r];
        if constexpr (EPI == 0) {
          ((bf16*)Cout)[(size_t)grow * N + gcol] = __float2bfloat16(v);
        } else if constexpr (EPI == 1) {
          v += bias[gcol];
          bf16 bv = __float2bfloat16(v);
          ((bf16*)Cout)[(size_t)grow * N + gcol] = bv;
          if ((grow & (Sc - 1)) != Sc - 1) aux[(size_t)(grow + 1) * N + gcol] = bv;
        } else if constexpr (EPI == 2) {
          v += bias[gcol] + resid[(size_t)grow * N + gcol];
          ((float*)Cout)[(size_t)grow * N + gcol] = v;
        } else if constexpr (EPI == 3) {
          const int head = gcol >> 6, d = gcol & 63;
          const int b = grow >> 11, s = grow & (Sc - 1);
          ((bf16*)Cout)[((size_t)((b * NHc + head) * HDc + d)) * Sc + s] = __float2bfloat16(v);
        } else {
          ((float*)Cout)[(size_t)grow * N + gcol] = v;
        }
      }
}

// ---------------- causal flash attention (swapped-operand, balanced) ----
// Q (pre-scaled), K: (b,h,s,d) bf16; Vt: (b,h,d,s) bf16; ctx: (b,s,h*64+d) bf16
// Block: 4 waves x 32 q-rows = 128 rows per pass; 2 mirrored passes (tile, 15-tile).
// grid = (bh=64, tile=8). Swapped QK^T: lane holds P[kv=c*16+lg*4+r][q=lrow].
__global__ __launch_bounds__(256) void k_attn(const bf16* __restrict__ Q,
                                              const bf16* __restrict__ Kg,
                                              const bf16* __restrict__ Vt,
                                              bf16* __restrict__ ctx) {
  // P transpose buffer: [wave][m][q=16][20 words] (80B row stride: aligned b128 reads)
  __shared__ __align__(16) uint32_t Pl[4][2][16][20];
  const int tid = threadIdx.x;
  const int w = tid >> 6, l = tid & 63;
  const int lrow = l & 15, lg = l >> 4, lk = lg * 8;
  const int bh = blockIdx.x;           // 0..63
  const int tile = blockIdx.y;         // 0..7
  const bf16* Qp = Q  + (size_t)bh * Sc * HDc;
  const bf16* Kp = Kg + (size_t)bh * Sc * HDc;
  const bf16* Vp = Vt + (size_t)bh * HDc * Sc;
  const int b = bh >> 5, h = bh & 31;

  for (int pass = 0; pass < 2; ++pass) {
    const int base = (pass == 0) ? tile * 128 : (Sc - 128 - tile * 128);
    const int q0 = base + w * 32;

    // Q fragments (B-operand): row=q (lane&15), k=d
    s16x8 qa[2][2];
#pragma unroll
    for (int m = 0; m < 2; ++m)
#pragma unroll
      for (int hf = 0; hf < 2; ++hf)
        qa[m][hf] = *(const s16x8*)&Qp[(size_t)(q0 + m * 16 + lrow) * 64 + hf * 32 + lk];

    f32x4 o[2][4] = {};                 // [m][d-tile]; lane: q=lrow, d=db*16+lg*4+r
    float mx[2] = {-1e30f, -1e30f};
    float ls[2] = {0.f, 0.f};

    // K fragments for kv0=0 (A-operand): row=kv, k=d
    s16x8 kc[4];
#pragma unroll
    for (int c = 0; c < 2; ++c)
#pragma unroll
      for (int hf = 0; hf < 2; ++hf)
        kc[c * 2 + hf] = *(const s16x8*)&Kp[(size_t)(c * 16 + lrow) * 64 + hf * 32 + lk];

    for (int kv0 = 0; kv0 <= q0; kv0 += 32) {
      // V frags for current kv0 (A-operand of PV): row=d, k=kv
      s16x8 vb[4];
#pragma unroll
      for (int db = 0; db < 4; ++db)
        vb[db] = *(const s16x8*)&Vp[(size_t)(db * 16 + lrow) * Sc + kv0 + lk];
      // prefetch next K tile
      const bool more = (kv0 < q0);
      s16x8 kn[4];
      if (more) {
#pragma unroll
        for (int c = 0; c < 2; ++c)
#pragma unroll
          for (int hf = 0; hf < 2; ++hf)
            kn[c * 2 + hf] =
                *(const s16x8*)&Kp[(size_t)(kv0 + 32 + c * 16 + lrow) * 64 + hf * 32 + lk];
      }
      const bool lastit = (kv0 == q0);

#pragma unroll
      for (int m = 0; m < 2; ++m) {
        // swapped QK^T: C[kv][q]
        f32x4 s0 = {}, s1 = {};
        s0 = mfma16(kc[0], qa[m][0], s0);
        s0 = mfma16(kc[1], qa[m][1], s0);
        s1 = mfma16(kc[2], qa[m][0], s1);
        s1 = mfma16(kc[3], qa[m][1], s1);

        if (lastit) {
          const int qq = q0 + m * 16 + lrow;
#pragma unroll
          for (int r = 0; r < 4; ++r) {
            if (kv0 + lg * 4 + r > qq)      s0[r] = -1e30f;
            if (kv0 + 16 + lg * 4 + r > qq) s1[r] = -1e30f;
          }
        }
        // online softmax: reduce over kv = in-register (8 vals) + xor16 + xor32
        float t = fmaxf(fmaxf(fmaxf(s0[0], s0[1]), fmaxf(s0[2], s0[3])),
                        fmaxf(fmaxf(s1[0], s1[1]), fmaxf(s1[2], s1[3])));
        t = fmaxf(t, __shfl_xor(t, 16, 64));
        t = fmaxf(t, __shfl_xor(t, 32, 64));
        const float mnew = fmaxf(mx[m], t);
        const float sold = __expf(mx[m] - mnew);
        mx[m] = mnew;
        float p0[4], p1[4];
#pragma unroll
        for (int r = 0; r < 4; ++r) {
          p0[r] = __expf(s0[r] - mnew);
          p1[r] = __expf(s1[r] - mnew);
        }
        float ps = (p0[0] + p0[1]) + (p0[2] + p0[3]) + (p1[0] + p1[1]) + (p1[2] + p1[3]);
        ps += __shfl_xor(ps, 16, 64);
        ps += __shfl_xor(ps, 32, 64);
        ls[m] = ls[m] * sold + ps;
#pragma unroll
        for (int db = 0; db < 4; ++db) o[m][db] *= sold;
        // P -> LDS transpose: row=q(lrow), word = kv/2 = c*8+lg*2+t'
        *(uint64_t*)&Pl[w][m][lrow][lg * 2] =
            (uint64_t)pkbf(p0[0], p0[1]) | ((uint64_t)pkbf(p0[2], p0[3]) << 32);
        *(uint64_t*)&Pl[w][m][lrow][8 + lg * 2] =
            (uint64_t)pkbf(p1[0], p1[1]) | ((uint64_t)pkbf(p1[2], p1[3]) << 32);
        // B-frag of P: P[q=lrow][kv=lg*8..lg*8+7]
        const s16x8 pb = *(const s16x8*)&Pl[w][m][lrow][lg * 4];
        // PV: C[d][q] += V^T[d][kv] * P[q][kv]
#pragma unroll
        for (int db = 0; db < 4; ++db)
          o[m][db] = mfma16(vb[db], pb, o[m][db]);
      }
      if (more) {
#pragma unroll
        for (int j = 0; j < 4; ++j) kc[j] = kn[j];
      }
    }
    // epilogue: lane holds q=lrow, d=db*16+lg*4+r -> pack 4 bf16 (8B) per store
#pragma unroll
    for (int m = 0; m < 2; ++m) {
      const float inv = 1.0f / ls[m];
      const int qrow = q0 + m * 16 + lrow;
      const size_t rowoff = ((size_t)(b * Sc + qrow)) * Hc + h * 64;
#pragma unroll
      for (int db = 0; db < 4; ++db) {
        uint64_t pk = (uint64_t)bfbits(o[m][db][0] * inv) |
                      ((uint64_t)bfbits(o[m][db][1] * inv) << 16) |
                      ((uint64_t)bfbits(o[m][db][2] * inv) << 32) |
                      ((uint64_t)bfbits(o[m][db][3] * inv) << 48);
        *(uint64_t*)&ctx[rowoff + db * 16 + lg * 4] = pk;
      }
    }
  }
}

// ---------------- host ----------------
extern "C" void kernel_launch(void* const* d_in, const int* in_sizes, int n_in,
                              void* d_out, int out_size, void* d_ws, size_t ws_size,
                              hipStream_t stream) {
  (void)in_sizes; (void)n_in; (void)out_size; (void)ws_size;
  const float* hs  = (const float*)d_in[0];
  const int*   pos = (const int*)d_in[1];
  const float* lf1 = (const float*)d_in[2];
  const float* lf2 = (const float*)d_in[3];
  const float* Wqk = (const float*)d_in[4];
  const float* Wv  = (const float*)d_in[5];
  const float* Wo  = (const float*)d_in[6];
  const float* c1w = (const float*)d_in[7];
  const float* c1b = (const float*)d_in[8];
  const float* c2w = (const float*)d_in[9];
  const float* c2b = (const float*)d_in[10];
  const float* lnw = (const float*)d_in[11];
  float* out = (float*)d_out;
  char*  ws  = (char*)d_ws;

  bf16* wvB   = (bf16*)(ws + OFF_WV);
  bf16* wqkB  = (bf16*)(ws + OFF_WQK);
  bf16* woB   = (bf16*)(ws + OFF_WO);
  bf16* w1B   = (bf16*)(ws + OFF_W1);
  bf16* w2B   = (bf16*)(ws + OFF_W2);
  bf16* hsB   = (bf16*)(ws + OFF_HS);
  bf16* xprB  = (bf16*)(ws + OFF_XPR);
  bf16* o1B   = (bf16*)(ws + OFF_O1);
  bf16* o1pB  = (bf16*)(ws + OFF_O1P);
  float* o2F  = (float*)(ws + OFF_O2);
  bf16* lfB   = (bf16*)(ws + OFF_LF);
  bf16* vtB   = (bf16*)(ws + OFF_VT);
  float* cosT = (float*)(ws + OFF_COS);
  float* sinT = (float*)(ws + OFF_SIN);
  bf16* qkB   = (bf16*)(ws + OFF_QK);
  bf16* qB    = (bf16*)(ws + OFF_Q);
  bf16* kB    = (bf16*)(ws + OFF_K);
  bf16* ctxB  = (bf16*)(ws + OFF_CTX);

  // YaRN inv_freq on host (fp64), matching the reference exactly
  InvF f;
  {
    const double base = 10000.0, scale = 2.0;
    const int hd = HDc;
    auto corr = [&](double nr) {
      return hd * log(8192.0 / (nr * 2.0 * M_PI)) / (2.0 * log(base));
    };
    double low = floor(corr(32.0)); if (low < 0) low = 0;
    double high = ceil(corr(1.0));  if (high > hd - 1) high = hd - 1;
    double hi = (low == high) ? high + 0.001 : high;
    for (int i = 0; i < 32; ++i) {
      double inv = 1.0 / pow(base, (2.0 * i) / hd);
      double ramp = ((double)i - low) / (hi - low);
      ramp = ramp < 0.0 ? 0.0 : (ramp > 1.0 ? 1.0 : ramp);
      double mask = 1.0 - ramp;
      f.v[i] = inv / ((1.0 - mask) * scale + mask);
    }
    f.mscale = 0.1 * log(scale) + 1.0;
  }

  // conversions / repacks / tables
  k_cvt<<<(Hc * Hc + 255) / 256, 256, 0, stream>>>(Wv, wvB, Hc * Hc);
  k_cvt<<<(2 * Hc * Hc + 255) / 256, 256, 0, stream>>>(Wqk, wqkB, 2 * Hc * Hc);
  k_cvt<<<(Hc * Hc + 255) / 256, 256, 0, stream>>>(Wo, woB, Hc * Hc);
  k_repack1<<<((Hc / 2) * 2 * Hc + 255) / 256, 256, 0, stream>>>(c1w, w1B);
  k_repack2<<<(Hc * Hc + 255) / 256, 256, 0, stream>>>(c2w, w2B);
  k_cvt_hs<<<(Mc * Hc + 255) / 256, 256, 0, stream>>>(hs, lf1, hsB, xprB);
  k_prefill_o1p<<<(Bc * (Hc / 2) + 255) / 256, 256, 0, stream>>>(lf2, o1pB);
  k_costab<<<(MAXPOS * HDc + 255) / 256, 256, 0, stream>>>(f, cosT, sinT);

  // conv1: o1 = [xprev|x] @ w1cat^T + b1   (dual store -> o1prev shifted)
  gemm_bt<1><<<dim3((Hc / 2) / 128, Mc / 128), 256, 0, stream>>>(
      xprB, hsB, Hc, w1B, 2 * Hc, Hc / 2, o1B, c1b, nullptr, o1pB);
  // v = hs @ Wv^T, stored transposed (b,h,d,s)
  gemm_bt<3><<<dim3(Hc / 128, Mc / 128), 256, 0, stream>>>(
      hsB, hsB, Hc, wvB, Hc, Hc, vtB, nullptr, nullptr, nullptr);
  // conv2: o2res = [o1prev|o1] @ w2cat^T + b2 + hidden  (fp32)
  gemm_bt<2><<<dim3(Hc / 128, Mc / 128), 256, 0, stream>>>(
      o1pB, o1B, Hc / 2, w2B, Hc, Hc, o2F, c2b, hs, nullptr);
  // lf = rmsnorm(o2res) * ln_w
  k_rmsnorm<<<Mc, 256, 0, stream>>>(o2F, lnw, lfB);
  // qk = lf @ Wqk^T   (bf16, over the o2res region)
  gemm_bt<0><<<dim3((2 * Hc) / 128, Mc / 128), 256, 0, stream>>>(
      lfB, lfB, Hc, wqkB, Hc, 2 * Hc, qkB, nullptr, nullptr, nullptr);
  // RoPE -> q (pre-scaled), k in (b,h,s,d)
  k_rope<<<(Mc * NHc * 32 + 255) / 256, 256, 0, stream>>>(qkB, pos, cosT, sinT, qB, kB);
  // causal flash attention -> ctx (b,s,h*64+d)
  k_attn<<<dim3(64, 8), 256, 0, stream>>>(qB, kB, vtB, ctxB);
  // out = ctx @ Wo^T  (fp32)
  gemm_bt<4><<<dim3(Hc / 128, Mc / 128), 256, 0, stream>>>(
      ctxB, ctxB, Hc, woB, Hc, Hc, out, nullptr, nullptr, nullptr);
}